// Round 12
// baseline (219.711 us; speedup 1.0000x reference)
//
#include <hip/hip_runtime.h>
#include <hip/hip_bf16.h>
#include <math.h>

typedef __attribute__((ext_vector_type(8))) short short8;
typedef __attribute__((ext_vector_type(4))) float f32x4;
typedef __attribute__((ext_vector_type(4))) unsigned int uint4v;

// Problem constants (B=8, S=4096, F=768, N=128)
constexpr int kF = 768;
constexpr int kN = 128;
constexpr int kB = 8;
constexpr int kS = 4096;
constexpr int kM = kB * kS;          // 32768 rows
constexpr int kChunks = 128;         // scan chunks along S (per batch)
constexpr int kClen = 32;

// Workspace layout (BYTE offsets), ~18.6 MB total.
// Bu [32768][256] f32 lives in d_out (y overwrites it later; Bu dead by then).
// NOTE: rounds 6-9 had finals(1MB-needed) overlapping carries/xbf (256KB
// reserved) — races resolved benignly by timing only. Fixed here; carries
// buffer eliminated by the fused scanAC.
constexpr size_t kOffBw      = 4096;      // Bw [256][768] bf16
constexpr size_t kOffCw      = 397312;    // Cw [768][256] bf16
constexpr size_t kOffFinals  = 790528;    // finals [1024][256] f32 = 1 MB
constexpr size_t kOffFlags   = 1839104;   // flags [1024] u32
constexpr size_t kOffXbf     = 1843200;   // x_bf16 [32768][256] ushort = 16 MB

// Software round-to-nearest-even f32->bf16. Round 5 regressed to absmax=0.35
// using __float2bfloat16 here (truncation-biased); f2bf is the proven-RNE path
// (absmax=0.0625 in rounds 2-4,6,8,9). Do not swap back without an A/B.
__device__ __forceinline__ unsigned short f2bf(float f) {
    unsigned int u = __builtin_bit_cast(unsigned int, f);
    u += 0x7fffu + ((u >> 16) & 1u);   // round-to-nearest-even
    return (unsigned short)(u >> 16);
}

__device__ __forceinline__ void gload16(const void* g, void* l) {
    __builtin_amdgcn_global_load_lds(
        (const __attribute__((address_space(1))) void*)g,
        (__attribute__((address_space(3))) void*)l, 16, 0, 0);
}

#define LGKM0_BAR() do { \
    asm volatile("s_waitcnt lgkmcnt(0)" ::: "memory"); \
    __builtin_amdgcn_s_barrier(); \
    __builtin_amdgcn_sched_barrier(0); \
} while (0)

__global__ __launch_bounds__(128)
void pre1(const float* __restrict__ log_A_real, const float* __restrict__ A_imag,
          const float* __restrict__ log_dt, float* __restrict__ ws) {
    int n = threadIdx.x;
    float dt = expf(log_dt[n]);
    float ar = -expf(log_A_real[n]);
    float ai = A_imag[n];
    float er = expf(ar * dt);
    float Ar = er * cosf(ai * dt);
    float Ai = er * sinf(ai * dt);
    // coef = (A_bar - 1) / (A_diag + 1e-8)
    float dr = ar + 1e-8f, di = ai;
    float inv = 1.0f / (dr * dr + di * di);
    float nr = Ar - 1.0f, ni = Ai;
    float cr = (nr * dr + ni * di) * inv;
    float ci = (ni * dr - nr * di) * inv;
    // P1 = A^32 by repeated multiply (matches scan semantics)
    float pr = 1.f, pi = 0.f;
    for (int i = 0; i < kClen; ++i) {
        float t = pr * Ar - pi * Ai;
        pi = pr * Ai + pi * Ar;
        pr = t;
    }
    ws[n] = Ar;        ws[128 + n] = Ai;
    ws[256 + n] = pr;  ws[384 + n] = pi;
    ws[512 + n] = cr;  ws[640 + n] = ci;
}

__global__ __launch_bounds__(256)
void pre2(const float* __restrict__ B_re, const float* __restrict__ B_im,
          const float* __restrict__ wsf, unsigned short* __restrict__ bw) {
    int id = blockIdx.x * 256 + threadIdx.x;   // 0 .. 256*768-1
    int c = id / kF;
    int f = id - c * kF;
    int n = c & 127;
    float cr = wsf[512 + n], ci = wsf[640 + n];
    float br = B_re[n * kF + f], bi = B_im[n * kF + f];
    float v = (c < 128) ? (cr * br - ci * bi) : (cr * bi + ci * br);
    bw[id] = f2bf(v);
}

__global__ __launch_bounds__(256)
void pre3(const float* __restrict__ C_re, const float* __restrict__ C_im,
          unsigned short* __restrict__ cw) {
    int id = blockIdx.x * 256 + threadIdx.x;   // 0 .. 768*256-1
    int f = id >> 8;
    int k = id & 255;
    float v = (k < 128) ? C_re[f * kN + k] : -C_im[f * kN + (k - 128)];
    cw[id] = f2bf(v);
}

// GEMM1: Bu[32768][256] = u[32768][768](f32) @ Bw^T (Bw [256][768] bf16)
// Round-12: FULL-N tile 128x256 (gx=1) -> A staged ONCE (per-CU staged bytes
// 1.15 -> 0.77 MB; rounds 6-9 showed duration ~ staged bytes/CU). 8 waves
// (2m x 4n of 64x64), BK=32, 24 steps, global_load_lds 3-slot ring, counted
// vmcnt(4), XOR-swizzle via pre-swizzled global source (r9 formulas).
// f32->bf16 RNE at fragment load -> bitwise-identical Bu, absmax 0.0625.
__global__ __launch_bounds__(512, 1)
void gemm1(const float* __restrict__ A,
           const unsigned short* __restrict__ W,
           float* __restrict__ Cout) {
    constexpr int K = kF, KT = K / 32;      // 24
    constexpr int SLOT = 32768;             // A 16KB + W 16KB
    __shared__ __align__(16) char smem[3 * SLOT];   // 96 KB

    const int m0 = blockIdx.x * 128;        // 256 blocks, n0 = 0

    const int t = threadIdx.x;
    const int wave = t >> 6, lane = t & 63;
    const int wr = wave >> 2, wc = wave & 3;   // 2x4 waves, each 64x64
    const int lr = lane & 15, lg = lane >> 4;
    const int l3 = lane >> 3, l7 = lane & 7;
    const int uswz = l7 ^ l3;                  // staging source 16B-unit swizzle

    // A: 16 gload instrs (2/wave), instr gi=wave*2+c covers rows gi*8..+7
    const float* aBase = A + (size_t)(m0 + wave * 16 + l3) * K + uswz * 4;
    // W: 16 gload instrs (2/wave), instr gi covers rows gi*16..+15 (2 rows/128B)
    const unsigned short* wBase =
        W + (size_t)(wave * 32 + l3 * 2 + (uswz >> 2)) * K + (uswz & 3) * 8;

    f32x4 acc[4][4] = {};

#define G1_ISSUE(kt_, slotbase_) do { \
    const float* aT_ = aBase + (size_t)(kt_) * 32; \
    const unsigned short* wT_ = wBase + (size_t)(kt_) * 32; \
    char* sA_ = (slotbase_); \
    char* sW_ = (slotbase_) + 16384; \
    gload16(aT_,          sA_ + (wave * 2 + 0) * 1024); \
    gload16(aT_ + 8 * K,  sA_ + (wave * 2 + 1) * 1024); \
    gload16(wT_,          sW_ + (wave * 2 + 0) * 1024); \
    gload16(wT_ + 16 * K, sW_ + (wave * 2 + 1) * 1024); \
} while (0)

#define G1_MMA_SLOT(slotbase_) do { \
    const char* sA_ = (slotbase_); \
    const char* sW_ = (slotbase_) + 16384; \
    short8 ah_[4], bh_[4]; \
    _Pragma("unroll") for (int i_ = 0; i_ < 4; ++i_) { \
        const int row_ = wr * 64 + i_ * 16 + lr; \
        const f32x4 fL_ = *(const f32x4*)(sA_ + row_ * 128 + (((lg * 2)     ^ (lr & 7)) * 16)); \
        const f32x4 fH_ = *(const f32x4*)(sA_ + row_ * 128 + (((lg * 2 + 1) ^ (lr & 7)) * 16)); \
        short8 v_; \
        _Pragma("unroll") for (int e_ = 0; e_ < 4; ++e_) { \
            v_[e_]     = (short)f2bf(fL_[e_]); \
            v_[4 + e_] = (short)f2bf(fH_[e_]); \
        } \
        ah_[i_] = v_; \
    } \
    _Pragma("unroll") for (int j_ = 0; j_ < 4; ++j_) { \
        const int row_ = wc * 64 + j_ * 16 + lr; \
        const int d_ = row_ >> 1; \
        const int u_ = (((lr & 1) * 4 + lg) ^ (d_ & 7)) * 16; \
        bh_[j_] = *(const short8*)(sW_ + d_ * 128 + u_); \
    } \
    _Pragma("unroll") for (int i_ = 0; i_ < 4; ++i_) \
    _Pragma("unroll") for (int j_ = 0; j_ < 4; ++j_) \
        acc[i_][j_] = __builtin_amdgcn_mfma_f32_16x16x32_bf16(ah_[i_], bh_[j_], acc[i_][j_], 0, 0, 0); \
} while (0)

    // prologue: tiles 0,1 in flight (4 gll instrs per wave each)
    G1_ISSUE(0, smem);
    G1_ISSUE(1, smem + SLOT);

    int slot = 0;
    for (int kt = 0; kt < KT; ++kt) {
        // own tile-kt loads done; tile kt+1 (4 instrs) may stay in flight
        if (kt < KT - 1) { asm volatile("s_waitcnt vmcnt(4)" ::: "memory"); }
        else             { asm volatile("s_waitcnt vmcnt(0)" ::: "memory"); }
        __builtin_amdgcn_s_barrier();        // all waves' tile-kt staged
        __builtin_amdgcn_sched_barrier(0);
        char* sb = smem + slot * SLOT;
        if (kt + 2 < KT) {
            char* nb = smem + (slot == 0 ? 2 * SLOT : (slot - 1) * SLOT);
            G1_ISSUE(kt + 2, nb);
        }
        G1_MMA_SLOT(sb);
        slot = (slot == 2) ? 0 : slot + 1;
    }

    // epilogue: C/D layout col=lane&15, row=(lane>>4)*4+reg [m89-verified]
#pragma unroll
    for (int i = 0; i < 4; ++i)
#pragma unroll
        for (int j = 0; j < 4; ++j) {
            const int col = wc * 64 + j * 16 + lr;
#pragma unroll
            for (int q = 0; q < 4; ++q) {
                const int row = m0 + wr * 64 + i * 16 + lg * 4 + q;
                Cout[(size_t)row * 256 + col] = acc[i][j][q];
            }
        }
#undef G1_ISSUE
#undef G1_MMA_SLOT
}

// Fused scan: holds the 32-step Bu chunk in registers; pass 1 = zero-init
// local scan (== scanA bitwise) -> publish final; spin-wait predecessors
// (all 1024 blocks co-resident: 128 thr, 0 LDS); carry composed with scanB's
// exact op order; pass 2 = seeded scan from registers (== scanC bitwise),
// emits x as bf16 RNE. Bu read ONCE instead of twice.
__global__ __launch_bounds__(128)
void scanAC(const float* __restrict__ Bu, const float* __restrict__ wsf,
            float* __restrict__ finals, unsigned int* __restrict__ flags,
            unsigned short* __restrict__ xbf) {
    const int n = threadIdx.x;
    const int blk = blockIdx.x;          // b*128 + c
    const int b = blk >> 7, c = blk & 127;
    const float Ar = wsf[n],       Ai = wsf[128 + n];
    const float P1r = wsf[256 + n], P1i = wsf[384 + n];
    const size_t base = ((size_t)(b * kS + c * kClen)) * 256;

    // hold the chunk in registers (statically indexed, rule #20)
    float br_[kClen], bi_[kClen];
#pragma unroll
    for (int s = 0; s < kClen; ++s) {
        br_[s] = Bu[base + (size_t)s * 256 + n];
        bi_[s] = Bu[base + (size_t)s * 256 + 128 + n];
    }

    // pass 1: zero-init scan -> chunk final (matches old scanA bitwise)
    float xr = 0.f, xi = 0.f;
#pragma unroll
    for (int s = 0; s < kClen; ++s) {
        float tr = Ar * xr - Ai * xi + br_[s];
        xi = Ar * xi + Ai * xr + bi_[s];
        xr = tr;
    }
    finals[(size_t)blk * 256 + n]       = xr;
    finals[(size_t)blk * 256 + 128 + n] = xi;
    __threadfence();
    __syncthreads();
    if (n == 0)
        __hip_atomic_store(&flags[blk], 1u, __ATOMIC_RELEASE, __HIP_MEMORY_SCOPE_AGENT);

    // wait for all predecessor chunks in this batch
    if (n < c) {
        const unsigned int* fp = &flags[b * kChunks + n];
        while (__hip_atomic_load(fp, __ATOMIC_ACQUIRE, __HIP_MEMORY_SCOPE_AGENT) == 0u)
            __builtin_amdgcn_s_sleep(2);
        __threadfence();
    }
    __syncthreads();

    // carry y_c = serial compose over j ascending (matches scanB bitwise)
    float yr = 0.f, yi = 0.f;
    for (int j = 0; j < c; ++j) {
        size_t o = (size_t)(b * kChunks + j) * 256;
        float fr = finals[o + n], fi = finals[o + 128 + n];
        float tr = P1r * yr - P1i * yi + fr;
        yi = P1r * yi + P1i * yr + fi;
        yr = tr;
    }

    // pass 2: seeded scan from registers (matches old scanC bitwise)
    xr = yr; xi = yi;
#pragma unroll
    for (int s = 0; s < kClen; ++s) {
        float tr = Ar * xr - Ai * xi + br_[s];
        xi = Ar * xi + Ai * xr + bi_[s];
        xr = tr;
        xbf[base + (size_t)s * 256 + n]       = f2bf(xr);
        xbf[base + (size_t)s * 256 + 128 + n] = f2bf(xi);
    }
}

// GEMM2: y[32768][768] = x_bf16[32768][256] @ Cw^T + D*u
// Round-9-exact (proven ~28 us): 128x128 tile, BK=32, 4 waves, lgkm-only
// barriers + 2-deep reg prefetch, m97 XCD swizzle (chunk-contiguous -> the 6
// sibling n-blocks of an m-panel share one XCD's L2).
__global__ __launch_bounds__(256, 3)
void gemm2(const unsigned short* __restrict__ A,
           const unsigned short* __restrict__ W,
           float* __restrict__ Cout,
           const float* __restrict__ Dp, const float* __restrict__ Up) {
    constexpr int K = 256, KT = 8, Nc = kF;
    __shared__ __align__(16) short As0[128 * 40];
    __shared__ __align__(16) short As1[128 * 40];
    __shared__ __align__(16) short Ws0[128 * 40];
    __shared__ __align__(16) short Ws1[128 * 40];

    // m97-style XCD swizzle (nwg = 1536, %8 == 0): each XCD gets a contiguous
    // chunk of tile indices; n-inner keeps panel siblings on one XCD.
    const int gx = gridDim.x;
    const int nwg = gx * gridDim.y;
    const int orig = blockIdx.y * gx + blockIdx.x;
    const int cpx = nwg >> 3;
    const int sw = (orig & 7) * cpx + (orig >> 3);
    const int m0 = (sw / gx) * 128;
    const int n0 = (sw % gx) * 128;

    const int t = threadIdx.x;
    const int sr = t >> 1, sh = t & 1;

    const int wave = t >> 6, lane = t & 63;
    const int wr = wave >> 1, wc = wave & 1;
    const int lr = lane & 15, lg = lane >> 4;

    f32x4 acc[4][4] = {};

    uint4v aA0, aA1, aB0, aB1;
    uint4v wA0, wA1, wB0, wB1;
    const unsigned short* aptr = A + (size_t)(m0 + sr) * K + sh * 16;
    const unsigned short* wptr = W + (size_t)(n0 + sr) * K + sh * 16;

#define G2_LOAD(SET, kt) do { \
    const unsigned short* p_ = aptr + (kt) * 32; \
    a##SET##0 = *(const uint4v*)p_; a##SET##1 = *(const uint4v*)(p_ + 8); \
    const unsigned short* q_ = wptr + (kt) * 32; \
    w##SET##0 = *(const uint4v*)q_; w##SET##1 = *(const uint4v*)(q_ + 8); \
} while (0)

#define G2_WRITE(Asb, Wsb, a0, a1, w0, w1) do { \
    const int o_ = sr * 40 + sh * 16; \
    *(short8*)(&Asb[o_])     = *(short8*)&a0; \
    *(short8*)(&Asb[o_ + 8]) = *(short8*)&a1; \
    *(short8*)(&Wsb[o_])     = *(short8*)&w0; \
    *(short8*)(&Wsb[o_ + 8]) = *(short8*)&w1; \
} while (0)

#define G2_MMA(Asb, Wsb) do { \
    short8 ah_[4], bh_[4]; \
    _Pragma("unroll") for (int i_ = 0; i_ < 4; ++i_) { \
        ah_[i_] = *(const short8*)(&Asb[(wr * 64 + i_ * 16 + lr) * 40 + lg * 8]); \
        bh_[i_] = *(const short8*)(&Wsb[(wc * 64 + i_ * 16 + lr) * 40 + lg * 8]); \
    } \
    _Pragma("unroll") for (int i_ = 0; i_ < 4; ++i_) \
    _Pragma("unroll") for (int j_ = 0; j_ < 4; ++j_) \
        acc[i_][j_] = __builtin_amdgcn_mfma_f32_16x16x32_bf16(ah_[i_], bh_[j_], acc[i_][j_], 0, 0, 0); \
} while (0)

    G2_LOAD(A, 0);
    G2_LOAD(B, 1);
    for (int kt = 0; kt < KT; kt += 2) {
        G2_WRITE(As0, Ws0, aA0, aA1, wA0, wA1);
        if (kt + 2 < KT) G2_LOAD(A, kt + 2);
        LGKM0_BAR();
        G2_MMA(As0, Ws0);
        G2_WRITE(As1, Ws1, aB0, aB1, wB0, wB1);
        if (kt + 3 < KT) G2_LOAD(B, kt + 3);
        LGKM0_BAR();
        G2_MMA(As1, Ws1);
    }

    // epilogue: C/D layout col=lane&15, row=(lane>>4)*4+reg
#pragma unroll
    for (int i = 0; i < 4; ++i)
#pragma unroll
        for (int j = 0; j < 4; ++j) {
            const int col = n0 + wc * 64 + j * 16 + lr;
#pragma unroll
            for (int q = 0; q < 4; ++q) {
                const int row = m0 + wr * 64 + i * 16 + lg * 4 + q;
                float v = acc[i][j][q];
                v = fmaf(Dp[col], Up[(size_t)row * Nc + col], v);
                Cout[(size_t)row * Nc + col] = v;
            }
        }
#undef G2_LOAD
#undef G2_WRITE
#undef G2_MMA
}

extern "C" void kernel_launch(void* const* d_in, const int* in_sizes, int n_in,
                              void* d_out, int out_size, void* d_ws, size_t ws_size,
                              hipStream_t stream) {
    const float* u          = (const float*)d_in[0];
    const float* log_A_real = (const float*)d_in[1];
    const float* A_imag     = (const float*)d_in[2];
    const float* B_re       = (const float*)d_in[3];
    const float* B_im       = (const float*)d_in[4];
    const float* C_re       = (const float*)d_in[5];
    const float* C_im       = (const float*)d_in[6];
    const float* D          = (const float*)d_in[7];
    const float* log_dt     = (const float*)d_in[8];

    char* wsb = (char*)d_ws;
    float* wsf            = (float*)wsb;
    unsigned short* bw    = (unsigned short*)(wsb + kOffBw);
    unsigned short* cw    = (unsigned short*)(wsb + kOffCw);
    float* finals         = (float*)(wsb + kOffFinals);
    unsigned int* flags   = (unsigned int*)(wsb + kOffFlags);
    unsigned short* xbf   = (unsigned short*)(wsb + kOffXbf);
    float* y              = (float*)d_out;
    // Bu (f32 [32768][256], 33.5 MB) lives in d_out; it is fully dead before
    // gemm2 overwrites d_out with y (gemm2 reads only xbf/u/weights).
    float* Bu             = (float*)d_out;

    hipMemsetAsync(flags, 0, kB * kChunks * sizeof(unsigned int), stream);

    pre1<<<1, 128, 0, stream>>>(log_A_real, A_imag, log_dt, wsf);
    pre2<<<(256 * kF) / 256, 256, 0, stream>>>(B_re, B_im, wsf, bw);
    pre3<<<(kF * 256) / 256, 256, 0, stream>>>(C_re, C_im, cw);

    // Bu = u @ Bw^T  (full-N tile: 256 blocks x 512 threads)
    gemm1<<<kM / 128, 512, 0, stream>>>(u, bw, Bu);

    // fused scan: Bu -> x(bf16), one Bu read
    scanAC<<<kB * kChunks, 128, 0, stream>>>(Bu, wsf, finals, flags, xbf);

    // y = x @ Cw^T + D*u
    gemm2<<<dim3(kF / 128, kM / 128), 256, 0, stream>>>(xbf, cw, y, D, u);
}

// Round 13
// 112.124 us; speedup vs baseline: 1.9595x; 1.9595x over previous
//
#include <hip/hip_runtime.h>
#include <hip/hip_bf16.h>
#include <math.h>

typedef __attribute__((ext_vector_type(8))) short short8;
typedef __attribute__((ext_vector_type(4))) float f32x4;
typedef __attribute__((ext_vector_type(4))) unsigned int uint4v;

// Problem constants (B=8, S=4096, F=768, N=128)
constexpr int kF = 768;
constexpr int kN = 128;
constexpr int kB = 8;
constexpr int kS = 4096;
constexpr int kM = kB * kS;          // 32768 rows
constexpr int kChunks = 128;         // scan chunks along S (per batch)
constexpr int kClen = 32;

// Workspace layout (BYTE offsets), ~19.6 MB. Bu f32 lives in d_out.
// finals/carries each fully sized 1 MB (r6-r9 overlapped them — latent race).
constexpr size_t kOffBw      = 4096;      // Bw [256][768] bf16
constexpr size_t kOffCw      = 397312;    // Cw [768][256] bf16
constexpr size_t kOffFinals  = 790528;    // finals [1024][256] f32
constexpr size_t kOffCarries = 1839104;   // carries [1024][256] f32
constexpr size_t kOffXbf     = 2887680;   // x_bf16 [32768][256]

// Software round-to-nearest-even f32->bf16. Round 5 regressed to absmax=0.35
// using __float2bfloat16 (truncation-biased); f2bf is the proven-RNE path.
__device__ __forceinline__ unsigned short f2bf(float f) {
    unsigned int u = __builtin_bit_cast(unsigned int, f);
    u += 0x7fffu + ((u >> 16) & 1u);   // round-to-nearest-even
    return (unsigned short)(u >> 16);
}

__device__ __forceinline__ void gload16(const void* g, void* l) {
    __builtin_amdgcn_global_load_lds(
        (const __attribute__((address_space(1))) void*)g,
        (__attribute__((address_space(3))) void*)l, 16, 0, 0);
}

#define LGKM0_BAR() do { \
    asm volatile("s_waitcnt lgkmcnt(0)" ::: "memory"); \
    __builtin_amdgcn_s_barrier(); \
    __builtin_amdgcn_sched_barrier(0); \
} while (0)

__global__ __launch_bounds__(128)
void pre1(const float* __restrict__ log_A_real, const float* __restrict__ A_imag,
          const float* __restrict__ log_dt, float* __restrict__ ws) {
    int n = threadIdx.x;
    float dt = expf(log_dt[n]);
    float ar = -expf(log_A_real[n]);
    float ai = A_imag[n];
    float er = expf(ar * dt);
    float Ar = er * cosf(ai * dt);
    float Ai = er * sinf(ai * dt);
    float dr = ar + 1e-8f, di = ai;
    float inv = 1.0f / (dr * dr + di * di);
    float nr = Ar - 1.0f, ni = Ai;
    float cr = (nr * dr + ni * di) * inv;
    float ci = (ni * dr - nr * di) * inv;
    float pr = 1.f, pi = 0.f;
    for (int i = 0; i < kClen; ++i) {
        float t = pr * Ar - pi * Ai;
        pi = pr * Ai + pi * Ar;
        pr = t;
    }
    ws[n] = Ar;        ws[128 + n] = Ai;
    ws[256 + n] = pr;  ws[384 + n] = pi;
    ws[512 + n] = cr;  ws[640 + n] = ci;
}

__global__ __launch_bounds__(256)
void pre2(const float* __restrict__ B_re, const float* __restrict__ B_im,
          const float* __restrict__ wsf, unsigned short* __restrict__ bw) {
    int id = blockIdx.x * 256 + threadIdx.x;   // 0 .. 256*768-1
    int c = id / kF;
    int f = id - c * kF;
    int n = c & 127;
    float cr = wsf[512 + n], ci = wsf[640 + n];
    float br = B_re[n * kF + f], bi = B_im[n * kF + f];
    float v = (c < 128) ? (cr * br - ci * bi) : (cr * bi + ci * br);
    bw[id] = f2bf(v);
}

__global__ __launch_bounds__(256)
void pre3(const float* __restrict__ C_re, const float* __restrict__ C_im,
          unsigned short* __restrict__ cw) {
    int id = blockIdx.x * 256 + threadIdx.x;   // 0 .. 768*256-1
    int f = id >> 8;
    int k = id & 255;
    float v = (k < 128) ? C_re[f * kN + k] : -C_im[f * kN + (k - 128)];
    cw[id] = f2bf(v);
}

// GEMM1 r13: Bu[32768][256] = u(f32->bf16 at frag load) @ Bw^T.
// Tile 64x256 full-N, 4 waves (1m x 4n, each 64x64), grid 512 (2 blocks/CU).
// ONLY A goes through LDS (8KB/step, 3-slot gload_lds ring, XOR-swizzled
// source); W fragments are read DIRECT from global into a 2-set register
// prefetch (W = 384 KB, L2-resident on every XCD) — removes the 98 MB of
// redundant W staging that shared the vmcnt/LDS path in r9/r12. A is read
// exactly once chip-wide (100 MB). vmcnt counts include the 4 W-loads:
// steady state = gload(kt+1):2 + W(kt):4 outstanding -> vmcnt(6); tail 4.
__global__ __launch_bounds__(256, 2)
void gemm1(const float* __restrict__ A,
           const unsigned short* __restrict__ W,
           float* __restrict__ Cout) {
    constexpr int K = kF, KT = K / 32;      // 24
    constexpr int SLOT = 8192;              // A: 64 rows x 128 B
    __shared__ __align__(16) char smem[3 * SLOT];   // 24 KB

    const int m0 = blockIdx.x * 64;         // 512 blocks, full-N (n0 = 0)

    const int t = threadIdx.x;
    const int wave = t >> 6, lane = t & 63;
    const int wc = wave;                     // wave's 64-col group
    const int lr = lane & 15, lg = lane >> 4;
    const int l3 = lane >> 3, l7 = lane & 7;
    const int uswz = l7 ^ l3;                // staging source 16B-unit swizzle

    // A staging: 8 gload instrs (2/wave); instr gi=wave*2+c covers rows gi*8..+7
    const float* aBase = A + (size_t)(m0 + wave * 16 + l3) * K + uswz * 4;
    // W fragment base: frag j, lane -> W[wc*64 + j*16 + lr][kt*32 + lg*8 ..+7]
    const unsigned short* wBase = W + (size_t)(wc * 64 + lr) * K + lg * 8;

    f32x4 acc[4][4] = {};
    short8 wSetA0, wSetA1, wSetA2, wSetA3;   // W prefetch set A (frag j=0..3)
    short8 wSetB0, wSetB1, wSetB2, wSetB3;   // W prefetch set B

#define G1_ISSUE(kt_, slotbase_) do { \
    const float* aT_ = aBase + (size_t)(kt_) * 32; \
    gload16(aT_,         (slotbase_) + (wave * 2 + 0) * 1024); \
    gload16(aT_ + 8 * K, (slotbase_) + (wave * 2 + 1) * 1024); \
} while (0)

#define G1_WLOAD(SET, kt_) do { \
    const unsigned short* wT_ = wBase + (size_t)(kt_) * 32; \
    wSet##SET##0 = *(const short8*)(wT_); \
    wSet##SET##1 = *(const short8*)(wT_ + 16 * K); \
    wSet##SET##2 = *(const short8*)(wT_ + 32 * K); \
    wSet##SET##3 = *(const short8*)(wT_ + 48 * K); \
} while (0)

#define G1_MMA(slotbase_, SET) do { \
    const char* sA_ = (slotbase_); \
    short8 ah_[4]; \
    _Pragma("unroll") for (int i_ = 0; i_ < 4; ++i_) { \
        const int row_ = i_ * 16 + lr; \
        const f32x4 fL_ = *(const f32x4*)(sA_ + row_ * 128 + (((lg * 2)     ^ (lr & 7)) * 16)); \
        const f32x4 fH_ = *(const f32x4*)(sA_ + row_ * 128 + (((lg * 2 + 1) ^ (lr & 7)) * 16)); \
        short8 v_; \
        _Pragma("unroll") for (int e_ = 0; e_ < 4; ++e_) { \
            v_[e_]     = (short)f2bf(fL_[e_]); \
            v_[4 + e_] = (short)f2bf(fH_[e_]); \
        } \
        ah_[i_] = v_; \
    } \
    _Pragma("unroll") for (int i_ = 0; i_ < 4; ++i_) { \
        acc[i_][0] = __builtin_amdgcn_mfma_f32_16x16x32_bf16(ah_[i_], wSet##SET##0, acc[i_][0], 0, 0, 0); \
        acc[i_][1] = __builtin_amdgcn_mfma_f32_16x16x32_bf16(ah_[i_], wSet##SET##1, acc[i_][1], 0, 0, 0); \
        acc[i_][2] = __builtin_amdgcn_mfma_f32_16x16x32_bf16(ah_[i_], wSet##SET##2, acc[i_][2], 0, 0, 0); \
        acc[i_][3] = __builtin_amdgcn_mfma_f32_16x16x32_bf16(ah_[i_], wSet##SET##3, acc[i_][3], 0, 0, 0); \
    } \
} while (0)

#define G1_SUBSTEP(kt_, CUR, NXT) do { \
    if ((kt_) < KT - 1) { asm volatile("s_waitcnt vmcnt(6)" ::: "memory"); } \
    else                { asm volatile("s_waitcnt vmcnt(4)" ::: "memory"); } \
    __builtin_amdgcn_s_barrier(); \
    __builtin_amdgcn_sched_barrier(0); \
    char* sb_ = smem + slot * SLOT; \
    if ((kt_) + 2 < KT) { \
        char* nb_ = smem + (slot == 0 ? 2 * SLOT : (slot - 1) * SLOT); \
        G1_ISSUE((kt_) + 2, nb_); \
    } \
    if ((kt_) + 1 < KT) G1_WLOAD(NXT, (kt_) + 1); \
    G1_MMA(sb_, CUR); \
    slot = (slot == 2) ? 0 : slot + 1; \
} while (0)

    // prologue: A tiles 0,1 in flight; W set A = tile 0
    G1_ISSUE(0, smem);
    G1_ISSUE(1, smem + SLOT);
    G1_WLOAD(A, 0);

    int slot = 0;
    for (int kt = 0; kt < KT; kt += 2) {
        G1_SUBSTEP(kt,     A, B);
        G1_SUBSTEP(kt + 1, B, A);
    }

    // epilogue: C/D layout col=lane&15, row=(lane>>4)*4+reg [m89-verified]
#pragma unroll
    for (int i = 0; i < 4; ++i)
#pragma unroll
        for (int j = 0; j < 4; ++j) {
            const int col = wc * 64 + j * 16 + lr;
#pragma unroll
            for (int q = 0; q < 4; ++q) {
                const int row = m0 + i * 16 + lg * 4 + q;
                Cout[(size_t)row * 256 + col] = acc[i][j][q];
            }
        }
#undef G1_ISSUE
#undef G1_WLOAD
#undef G1_MMA
#undef G1_SUBSTEP
}

// Phase A: per (b, chunk), local scan with zero init; save chunk-final state.
__global__ __launch_bounds__(128)
void scanA(const float* __restrict__ Bu, const float* __restrict__ wsc,
           float* __restrict__ finals) {
    int n = threadIdx.x;
    int blk = blockIdx.x;            // b*kChunks + c
    int b = blk >> 7, c = blk & 127;
    float Ar = wsc[n], Ai = wsc[128 + n];
    float xr = 0.f, xi = 0.f;
    size_t base = ((size_t)(b * kS + c * kClen)) * 256;
#pragma unroll 8
    for (int s = 0; s < kClen; ++s) {
        float br = Bu[base + n], bi = Bu[base + 128 + n];
        float tr = Ar * xr - Ai * xi + br;
        xi = Ar * xi + Ai * xr + bi;
        xr = tr;
        base += 256;
    }
    finals[(size_t)blk * 256 + n] = xr;
    finals[(size_t)blk * 256 + 128 + n] = xi;
}

// Phase B: serial scan over chunk finals -> exclusive carries.
__global__ __launch_bounds__(128)
void scanB(const float* __restrict__ finals, const float* __restrict__ ws,
           float* __restrict__ carries) {
    int n = threadIdx.x;
    int b = blockIdx.x;
    float Pr = ws[256 + n], Pi = ws[384 + n];
    float xr = 0.f, xi = 0.f;
#pragma unroll 8
    for (int c = 0; c < kChunks; ++c) {
        size_t o = ((size_t)(b * kChunks + c)) * 256;
        carries[o + n] = xr;
        carries[o + 128 + n] = xi;
        float fr = finals[o + n], fi = finals[o + 128 + n];
        float tr = Pr * xr - Pi * xi + fr;
        xi = Pr * xi + Pi * xr + fi;
        xr = tr;
    }
}

// Phase C: redo local scan seeded with carry; emit x as bf16 RNE (GEMM2 input).
__global__ __launch_bounds__(128)
void scanC(const float* __restrict__ Bu, const float* __restrict__ wsc,
           const float* __restrict__ carries, unsigned short* __restrict__ xbf) {
    int n = threadIdx.x;
    int blk = blockIdx.x;
    int b = blk >> 7, c = blk & 127;
    float Ar = wsc[n], Ai = wsc[128 + n];
    size_t co = (size_t)blk * 256;
    float xr = carries[co + n], xi = carries[co + 128 + n];
    size_t base = ((size_t)(b * kS + c * kClen)) * 256;
#pragma unroll 4
    for (int s = 0; s < kClen; ++s) {
        float br = Bu[base + n], bi = Bu[base + 128 + n];
        float tr = Ar * xr - Ai * xi + br;
        xi = Ar * xi + Ai * xr + bi;
        xr = tr;
        xbf[base + n]       = f2bf(xr);
        xbf[base + 128 + n] = f2bf(xi);
        base += 256;
    }
}

// GEMM2: y[32768][768] = x_bf16[32768][256] @ Cw^T + D*u
// Round-9-exact (proven ~28 us): 128x128 tile, BK=32, 4 waves, lgkm-only
// barriers + 2-deep reg prefetch, m97 chunk XCD swizzle.
__global__ __launch_bounds__(256, 3)
void gemm2(const unsigned short* __restrict__ A,
           const unsigned short* __restrict__ W,
           float* __restrict__ Cout,
           const float* __restrict__ Dp, const float* __restrict__ Up) {
    constexpr int K = 256, KT = 8, Nc = kF;
    __shared__ __align__(16) short As0[128 * 40];
    __shared__ __align__(16) short As1[128 * 40];
    __shared__ __align__(16) short Ws0[128 * 40];
    __shared__ __align__(16) short Ws1[128 * 40];

    const int gx = gridDim.x;
    const int nwg = gx * gridDim.y;
    const int orig = blockIdx.y * gx + blockIdx.x;
    const int cpx = nwg >> 3;
    const int sw = (orig & 7) * cpx + (orig >> 3);
    const int m0 = (sw / gx) * 128;
    const int n0 = (sw % gx) * 128;

    const int t = threadIdx.x;
    const int sr = t >> 1, sh = t & 1;

    const int wave = t >> 6, lane = t & 63;
    const int wr = wave >> 1, wc = wave & 1;
    const int lr = lane & 15, lg = lane >> 4;

    f32x4 acc[4][4] = {};

    uint4v aA0, aA1, aB0, aB1;
    uint4v wA0, wA1, wB0, wB1;
    const unsigned short* aptr = A + (size_t)(m0 + sr) * K + sh * 16;
    const unsigned short* wptr = W + (size_t)(n0 + sr) * K + sh * 16;

#define G2_LOAD(SET, kt) do { \
    const unsigned short* p_ = aptr + (kt) * 32; \
    a##SET##0 = *(const uint4v*)p_; a##SET##1 = *(const uint4v*)(p_ + 8); \
    const unsigned short* q_ = wptr + (kt) * 32; \
    w##SET##0 = *(const uint4v*)q_; w##SET##1 = *(const uint4v*)(q_ + 8); \
} while (0)

#define G2_WRITE(Asb, Wsb, a0, a1, w0, w1) do { \
    const int o_ = sr * 40 + sh * 16; \
    *(short8*)(&Asb[o_])     = *(short8*)&a0; \
    *(short8*)(&Asb[o_ + 8]) = *(short8*)&a1; \
    *(short8*)(&Wsb[o_])     = *(short8*)&w0; \
    *(short8*)(&Wsb[o_ + 8]) = *(short8*)&w1; \
} while (0)

#define G2_MMA(Asb, Wsb) do { \
    short8 ah_[4], bh_[4]; \
    _Pragma("unroll") for (int i_ = 0; i_ < 4; ++i_) { \
        ah_[i_] = *(const short8*)(&Asb[(wr * 64 + i_ * 16 + lr) * 40 + lg * 8]); \
        bh_[i_] = *(const short8*)(&Wsb[(wc * 64 + i_ * 16 + lr) * 40 + lg * 8]); \
    } \
    _Pragma("unroll") for (int i_ = 0; i_ < 4; ++i_) \
    _Pragma("unroll") for (int j_ = 0; j_ < 4; ++j_) \
        acc[i_][j_] = __builtin_amdgcn_mfma_f32_16x16x32_bf16(ah_[i_], bh_[j_], acc[i_][j_], 0, 0, 0); \
} while (0)

    G2_LOAD(A, 0);
    G2_LOAD(B, 1);
    for (int kt = 0; kt < KT; kt += 2) {
        G2_WRITE(As0, Ws0, aA0, aA1, wA0, wA1);
        if (kt + 2 < KT) G2_LOAD(A, kt + 2);
        LGKM0_BAR();
        G2_MMA(As0, Ws0);
        G2_WRITE(As1, Ws1, aB0, aB1, wB0, wB1);
        if (kt + 3 < KT) G2_LOAD(B, kt + 3);
        LGKM0_BAR();
        G2_MMA(As1, Ws1);
    }

#pragma unroll
    for (int i = 0; i < 4; ++i)
#pragma unroll
        for (int j = 0; j < 4; ++j) {
            const int col = n0 + wc * 64 + j * 16 + lr;
#pragma unroll
            for (int q = 0; q < 4; ++q) {
                const int row = m0 + wr * 64 + i * 16 + lg * 4 + q;
                float v = acc[i][j][q];
                v = fmaf(Dp[col], Up[(size_t)row * Nc + col], v);
                Cout[(size_t)row * Nc + col] = v;
            }
        }
#undef G2_LOAD
#undef G2_WRITE
#undef G2_MMA
}

extern "C" void kernel_launch(void* const* d_in, const int* in_sizes, int n_in,
                              void* d_out, int out_size, void* d_ws, size_t ws_size,
                              hipStream_t stream) {
    const float* u          = (const float*)d_in[0];
    const float* log_A_real = (const float*)d_in[1];
    const float* A_imag     = (const float*)d_in[2];
    const float* B_re       = (const float*)d_in[3];
    const float* B_im       = (const float*)d_in[4];
    const float* C_re       = (const float*)d_in[5];
    const float* C_im       = (const float*)d_in[6];
    const float* D          = (const float*)d_in[7];
    const float* log_dt     = (const float*)d_in[8];

    char* wsb = (char*)d_ws;
    float* wsf            = (float*)wsb;
    unsigned short* bw    = (unsigned short*)(wsb + kOffBw);
    unsigned short* cw    = (unsigned short*)(wsb + kOffCw);
    float* finals         = (float*)(wsb + kOffFinals);
    float* carries        = (float*)(wsb + kOffCarries);
    unsigned short* xbf   = (unsigned short*)(wsb + kOffXbf);
    float* y              = (float*)d_out;
    // Bu (f32 [32768][256], 33.5 MB) lives in d_out; it is fully dead before
    // gemm2 overwrites d_out with y (gemm2 reads only xbf/u/weights).
    float* Bu             = (float*)d_out;

    pre1<<<1, 128, 0, stream>>>(log_A_real, A_imag, log_dt, wsf);
    pre2<<<(256 * kF) / 256, 256, 0, stream>>>(B_re, B_im, wsf, bw);
    pre3<<<(kF * 256) / 256, 256, 0, stream>>>(C_re, C_im, cw);

    // Bu = u @ Bw^T  (64x256 full-N tiles: 512 blocks x 256 threads)
    gemm1<<<kM / 64, 256, 0, stream>>>(u, bw, Bu);

    scanA<<<kB * kChunks, 128, 0, stream>>>(Bu, wsf, finals);
    scanB<<<kB, 128, 0, stream>>>(finals, wsf, carries);
    scanC<<<kB * kChunks, 128, 0, stream>>>(Bu, wsf, carries, xbf);

    // y = x @ Cw^T + D*u
    gemm2<<<dim3(kF / 128, kM / 128), 256, 0, stream>>>(xbf, cw, y, D, u);
}

// Round 14
// 96.183 us; speedup vs baseline: 2.2843x; 1.1657x over previous
//
#include <hip/hip_runtime.h>
#include <hip/hip_bf16.h>
#include <math.h>

typedef __attribute__((ext_vector_type(8))) short short8;
typedef __attribute__((ext_vector_type(4))) float f32x4;
typedef __attribute__((ext_vector_type(4))) unsigned int uint4v;

// Problem constants (B=8, S=4096, F=768, N=128)
constexpr int kF = 768;
constexpr int kN = 128;
constexpr int kB = 8;
constexpr int kS = 4096;
constexpr int kM = kB * kS;          // 32768 rows
constexpr int kChunks = 128;         // scan chunks along S (per batch)
constexpr int kClen = 32;

// Workspace layout (BYTE offsets), ~36.5 MB (round 1 used 37.2 MB OK).
// Round 14: Bu is bf16 (16.8 MB) in ws — d_out holds only y.
constexpr size_t kOffBw      = 4096;      // Bw [256][768] bf16
constexpr size_t kOffCw      = 397312;    // Cw [768][256] bf16
constexpr size_t kOffFinals  = 790528;    // finals [1024][256] f32
constexpr size_t kOffCarries = 1839104;   // carries [1024][256] f32
constexpr size_t kOffXbf     = 2887680;   // x_bf16 [32768][256]
constexpr size_t kOffBubf    = 19664896;  // Bu_bf16 [32768][256]

// Software round-to-nearest-even f32->bf16. Round 5 regressed to absmax=0.35
// using __float2bfloat16 (truncation-biased); f2bf is the proven-RNE path.
__device__ __forceinline__ unsigned short f2bf(float f) {
    unsigned int u = __builtin_bit_cast(unsigned int, f);
    u += 0x7fffu + ((u >> 16) & 1u);   // round-to-nearest-even
    return (unsigned short)(u >> 16);
}
__device__ __forceinline__ float bf2f(unsigned short s) {
    unsigned int u = ((unsigned int)s) << 16;
    return __builtin_bit_cast(float, u);
}

__device__ __forceinline__ void gload16(const void* g, void* l) {
    __builtin_amdgcn_global_load_lds(
        (const __attribute__((address_space(1))) void*)g,
        (__attribute__((address_space(3))) void*)l, 16, 0, 0);
}

#define LGKM0_BAR() do { \
    asm volatile("s_waitcnt lgkmcnt(0)" ::: "memory"); \
    __builtin_amdgcn_s_barrier(); \
    __builtin_amdgcn_sched_barrier(0); \
} while (0)

__global__ __launch_bounds__(128)
void pre1(const float* __restrict__ log_A_real, const float* __restrict__ A_imag,
          const float* __restrict__ log_dt, float* __restrict__ ws) {
    int n = threadIdx.x;
    float dt = expf(log_dt[n]);
    float ar = -expf(log_A_real[n]);
    float ai = A_imag[n];
    float er = expf(ar * dt);
    float Ar = er * cosf(ai * dt);
    float Ai = er * sinf(ai * dt);
    float dr = ar + 1e-8f, di = ai;
    float inv = 1.0f / (dr * dr + di * di);
    float nr = Ar - 1.0f, ni = Ai;
    float cr = (nr * dr + ni * di) * inv;
    float ci = (ni * dr - nr * di) * inv;
    float pr = 1.f, pi = 0.f;
    for (int i = 0; i < kClen; ++i) {
        float t = pr * Ar - pi * Ai;
        pi = pr * Ai + pi * Ar;
        pr = t;
    }
    ws[n] = Ar;        ws[128 + n] = Ai;
    ws[256 + n] = pr;  ws[384 + n] = pi;
    ws[512 + n] = cr;  ws[640 + n] = ci;
}

__global__ __launch_bounds__(256)
void pre2(const float* __restrict__ B_re, const float* __restrict__ B_im,
          const float* __restrict__ wsf, unsigned short* __restrict__ bw) {
    int id = blockIdx.x * 256 + threadIdx.x;   // 0 .. 256*768-1
    int c = id / kF;
    int f = id - c * kF;
    int n = c & 127;
    float cr = wsf[512 + n], ci = wsf[640 + n];
    float br = B_re[n * kF + f], bi = B_im[n * kF + f];
    float v = (c < 128) ? (cr * br - ci * bi) : (cr * bi + ci * br);
    bw[id] = f2bf(v);
}

__global__ __launch_bounds__(256)
void pre3(const float* __restrict__ C_re, const float* __restrict__ C_im,
          unsigned short* __restrict__ cw) {
    int id = blockIdx.x * 256 + threadIdx.x;   // 0 .. 768*256-1
    int f = id >> 8;
    int k = id & 255;
    float v = (k < 128) ? C_re[f * kN + k] : -C_im[f * kN + (k - 128)];
    cw[id] = f2bf(v);
}

// GEMM1: Bu_bf16[32768][256] = u[32768][768](f32) @ Bw^T (Bw [256][768] bf16)
// Round-9-exact core (best measured: ~51us): 128x128 tile, BK=32, 24 steps,
// global_load_lds direct staging, 3-slot LDS ring, counted vmcnt(6), m97
// XCD swizzle, XOR-swizzle via pre-swizzled global source. Round-14 change:
// epilogue emits Bu as bf16 RNE (halves write bytes; scan noise analyzed
// safe: linear scan preserves relative error ~2^-9, same order as existing
// x->bf16 rounding).
__global__ __launch_bounds__(256, 2)
void gemm1(const float* __restrict__ A,
           const unsigned short* __restrict__ W,
           unsigned short* __restrict__ Cout) {
    constexpr int K = kF, KT = K / 32;      // 24
    constexpr int SLOT = 24576;             // A 16KB + W 8KB
    __shared__ __align__(16) char smem[3 * SLOT];

    // m97 XCD swizzle (nwg = 512, %8 == 0)
    const int gx = gridDim.x;
    const int nwg = gx * gridDim.y;
    const int orig = blockIdx.y * gx + blockIdx.x;
    const int cpx = nwg >> 3;
    const int sw = (orig & 7) * cpx + (orig >> 3);
    const int m0 = (sw / gx) * 128;
    const int n0 = (sw % gx) * 128;

    const int t = threadIdx.x;
    const int wave = t >> 6, lane = t & 63;
    const int wr = wave >> 1, wc = wave & 1;   // 2x2 waves, each 64x64
    const int lr = lane & 15, lg = lane >> 4;
    const int l3 = lane >> 3, l7 = lane & 7;
    const int uswz = l7 ^ l3;                  // staging source 16B-unit swizzle

    // per-lane global staging bases (instr c adds c*rows*K; tile kt adds kt*32)
    const float* aBase = A + (size_t)(m0 + wave * 32 + l3) * K + uswz * 4;
    const unsigned short* wBase =
        W + (size_t)(n0 + wave * 32 + l3 * 2 + (uswz >> 2)) * K + (uswz & 3) * 8;

    f32x4 acc[4][4] = {};

#define G1_ISSUE(kt_, slotbase_) do { \
    const float* aT_ = aBase + (size_t)(kt_) * 32; \
    const unsigned short* wT_ = wBase + (size_t)(kt_) * 32; \
    char* sA_ = (slotbase_); \
    char* sW_ = (slotbase_) + 16384; \
    _Pragma("unroll") for (int c_ = 0; c_ < 4; ++c_) \
        gload16(aT_ + c_ * 8 * K, sA_ + (wave * 4 + c_) * 1024); \
    _Pragma("unroll") for (int c_ = 0; c_ < 2; ++c_) \
        gload16(wT_ + c_ * 16 * K, sW_ + (wave * 2 + c_) * 1024); \
} while (0)

#define G1_MMA_SLOT(slotbase_) do { \
    const char* sA_ = (slotbase_); \
    const char* sW_ = (slotbase_) + 16384; \
    short8 ah_[4], bh_[4]; \
    _Pragma("unroll") for (int i_ = 0; i_ < 4; ++i_) { \
        const int row_ = wr * 64 + i_ * 16 + lr; \
        const f32x4 fL_ = *(const f32x4*)(sA_ + row_ * 128 + (((lg * 2)     ^ (lr & 7)) * 16)); \
        const f32x4 fH_ = *(const f32x4*)(sA_ + row_ * 128 + (((lg * 2 + 1) ^ (lr & 7)) * 16)); \
        short8 v_; \
        _Pragma("unroll") for (int e_ = 0; e_ < 4; ++e_) { \
            v_[e_]     = (short)f2bf(fL_[e_]); \
            v_[4 + e_] = (short)f2bf(fH_[e_]); \
        } \
        ah_[i_] = v_; \
    } \
    _Pragma("unroll") for (int j_ = 0; j_ < 4; ++j_) { \
        const int row_ = wc * 64 + j_ * 16 + lr; \
        const int d_ = row_ >> 1; \
        const int u_ = (((lr & 1) * 4 + lg) ^ (d_ & 7)) * 16; \
        bh_[j_] = *(const short8*)(sW_ + d_ * 128 + u_); \
    } \
    _Pragma("unroll") for (int i_ = 0; i_ < 4; ++i_) \
    _Pragma("unroll") for (int j_ = 0; j_ < 4; ++j_) \
        acc[i_][j_] = __builtin_amdgcn_mfma_f32_16x16x32_bf16(ah_[i_], bh_[j_], acc[i_][j_], 0, 0, 0); \
} while (0)

    // prologue: tiles 0,1 in flight (6 gll instrs per wave each)
    G1_ISSUE(0, smem);
    G1_ISSUE(1, smem + SLOT);

    int slot = 0;
    for (int kt = 0; kt < KT; ++kt) {
        if (kt < KT - 1) { asm volatile("s_waitcnt vmcnt(6)" ::: "memory"); }
        else             { asm volatile("s_waitcnt vmcnt(0)" ::: "memory"); }
        __builtin_amdgcn_s_barrier();        // all waves' tile-kt staged
        __builtin_amdgcn_sched_barrier(0);
        char* sb = smem + slot * SLOT;
        if (kt + 2 < KT) {
            char* nb = smem + (slot == 0 ? 2 * SLOT : (slot - 1) * SLOT);
            G1_ISSUE(kt + 2, nb);
        }
        G1_MMA_SLOT(sb);
        slot = (slot == 2) ? 0 : slot + 1;
    }

    // epilogue: C/D layout col=lane&15, row=(lane>>4)*4+reg; emit bf16 RNE
#pragma unroll
    for (int i = 0; i < 4; ++i)
#pragma unroll
        for (int j = 0; j < 4; ++j) {
            const int col = n0 + wc * 64 + j * 16 + lr;
#pragma unroll
            for (int q = 0; q < 4; ++q) {
                const int row = m0 + wr * 64 + i * 16 + lg * 4 + q;
                Cout[(size_t)row * 256 + col] = f2bf(acc[i][j][q]);
            }
        }
#undef G1_ISSUE
#undef G1_MMA_SLOT
}

// Phase A: per (b, chunk), local scan (bf16 Bu -> f32 state); save chunk final.
__global__ __launch_bounds__(128)
void scanA(const unsigned short* __restrict__ Bu, const float* __restrict__ wsc,
           float* __restrict__ finals) {
    int n = threadIdx.x;
    int blk = blockIdx.x;            // b*kChunks + c
    int b = blk >> 7, c = blk & 127;
    float Ar = wsc[n], Ai = wsc[128 + n];
    float xr = 0.f, xi = 0.f;
    size_t base = ((size_t)(b * kS + c * kClen)) * 256;
#pragma unroll 8
    for (int s = 0; s < kClen; ++s) {
        float br = bf2f(Bu[base + n]), bi = bf2f(Bu[base + 128 + n]);
        float tr = Ar * xr - Ai * xi + br;
        xi = Ar * xi + Ai * xr + bi;
        xr = tr;
        base += 256;
    }
    finals[(size_t)blk * 256 + n] = xr;
    finals[(size_t)blk * 256 + 128 + n] = xi;
}

// Phase B: serial scan over chunk finals -> exclusive carries.
__global__ __launch_bounds__(128)
void scanB(const float* __restrict__ finals, const float* __restrict__ ws,
           float* __restrict__ carries) {
    int n = threadIdx.x;
    int b = blockIdx.x;
    float Pr = ws[256 + n], Pi = ws[384 + n];
    float xr = 0.f, xi = 0.f;
#pragma unroll 8
    for (int c = 0; c < kChunks; ++c) {
        size_t o = ((size_t)(b * kChunks + c)) * 256;
        carries[o + n] = xr;
        carries[o + 128 + n] = xi;
        float fr = finals[o + n], fi = finals[o + 128 + n];
        float tr = Pr * xr - Pi * xi + fr;
        xi = Pr * xi + Pi * xr + fi;
        xr = tr;
    }
}

// Phase C: seeded local scan (bf16 Bu); emit x as bf16 RNE (GEMM2 input).
__global__ __launch_bounds__(128)
void scanC(const unsigned short* __restrict__ Bu, const float* __restrict__ wsc,
           const float* __restrict__ carries, unsigned short* __restrict__ xbf) {
    int n = threadIdx.x;
    int blk = blockIdx.x;
    int b = blk >> 7, c = blk & 127;
    float Ar = wsc[n], Ai = wsc[128 + n];
    size_t co = (size_t)blk * 256;
    float xr = carries[co + n], xi = carries[co + 128 + n];
    size_t base = ((size_t)(b * kS + c * kClen)) * 256;
#pragma unroll 4
    for (int s = 0; s < kClen; ++s) {
        float br = bf2f(Bu[base + n]), bi = bf2f(Bu[base + 128 + n]);
        float tr = Ar * xr - Ai * xi + br;
        xi = Ar * xi + Ai * xr + bi;
        xr = tr;
        xbf[base + n]       = f2bf(xr);
        xbf[base + 128 + n] = f2bf(xi);
        base += 256;
    }
}

// GEMM2: y[32768][768] = x_bf16[32768][256] @ Cw^T + D*u
// Round-9-exact (proven ~28 us): 128x128 tile, BK=32, 4 waves, lgkm-only
// barriers + 2-deep reg prefetch, m97 chunk XCD swizzle.
__global__ __launch_bounds__(256, 3)
void gemm2(const unsigned short* __restrict__ A,
           const unsigned short* __restrict__ W,
           float* __restrict__ Cout,
           const float* __restrict__ Dp, const float* __restrict__ Up) {
    constexpr int K = 256, KT = 8, Nc = kF;
    __shared__ __align__(16) short As0[128 * 40];
    __shared__ __align__(16) short As1[128 * 40];
    __shared__ __align__(16) short Ws0[128 * 40];
    __shared__ __align__(16) short Ws1[128 * 40];

    const int gx = gridDim.x;
    const int nwg = gx * gridDim.y;
    const int orig = blockIdx.y * gx + blockIdx.x;
    const int cpx = nwg >> 3;
    const int sw = (orig & 7) * cpx + (orig >> 3);
    const int m0 = (sw / gx) * 128;
    const int n0 = (sw % gx) * 128;

    const int t = threadIdx.x;
    const int sr = t >> 1, sh = t & 1;

    const int wave = t >> 6, lane = t & 63;
    const int wr = wave >> 1, wc = wave & 1;
    const int lr = lane & 15, lg = lane >> 4;

    f32x4 acc[4][4] = {};

    uint4v aA0, aA1, aB0, aB1;
    uint4v wA0, wA1, wB0, wB1;
    const unsigned short* aptr = A + (size_t)(m0 + sr) * K + sh * 16;
    const unsigned short* wptr = W + (size_t)(n0 + sr) * K + sh * 16;

#define G2_LOAD(SET, kt) do { \
    const unsigned short* p_ = aptr + (kt) * 32; \
    a##SET##0 = *(const uint4v*)p_; a##SET##1 = *(const uint4v*)(p_ + 8); \
    const unsigned short* q_ = wptr + (kt) * 32; \
    w##SET##0 = *(const uint4v*)q_; w##SET##1 = *(const uint4v*)(q_ + 8); \
} while (0)

#define G2_WRITE(Asb, Wsb, a0, a1, w0, w1) do { \
    const int o_ = sr * 40 + sh * 16; \
    *(short8*)(&Asb[o_])     = *(short8*)&a0; \
    *(short8*)(&Asb[o_ + 8]) = *(short8*)&a1; \
    *(short8*)(&Wsb[o_])     = *(short8*)&w0; \
    *(short8*)(&Wsb[o_ + 8]) = *(short8*)&w1; \
} while (0)

#define G2_MMA(Asb, Wsb) do { \
    short8 ah_[4], bh_[4]; \
    _Pragma("unroll") for (int i_ = 0; i_ < 4; ++i_) { \
        ah_[i_] = *(const short8*)(&Asb[(wr * 64 + i_ * 16 + lr) * 40 + lg * 8]); \
        bh_[i_] = *(const short8*)(&Wsb[(wc * 64 + i_ * 16 + lr) * 40 + lg * 8]); \
    } \
    _Pragma("unroll") for (int i_ = 0; i_ < 4; ++i_) \
    _Pragma("unroll") for (int j_ = 0; j_ < 4; ++j_) \
        acc[i_][j_] = __builtin_amdgcn_mfma_f32_16x16x32_bf16(ah_[i_], bh_[j_], acc[i_][j_], 0, 0, 0); \
} while (0)

    G2_LOAD(A, 0);
    G2_LOAD(B, 1);
    for (int kt = 0; kt < KT; kt += 2) {
        G2_WRITE(As0, Ws0, aA0, aA1, wA0, wA1);
        if (kt + 2 < KT) G2_LOAD(A, kt + 2);
        LGKM0_BAR();
        G2_MMA(As0, Ws0);
        G2_WRITE(As1, Ws1, aB0, aB1, wB0, wB1);
        if (kt + 3 < KT) G2_LOAD(B, kt + 3);
        LGKM0_BAR();
        G2_MMA(As1, Ws1);
    }

#pragma unroll
    for (int i = 0; i < 4; ++i)
#pragma unroll
        for (int j = 0; j < 4; ++j) {
            const int col = n0 + wc * 64 + j * 16 + lr;
#pragma unroll
            for (int q = 0; q < 4; ++q) {
                const int row = m0 + wr * 64 + i * 16 + lg * 4 + q;
                float v = acc[i][j][q];
                v = fmaf(Dp[col], Up[(size_t)row * Nc + col], v);
                Cout[(size_t)row * Nc + col] = v;
            }
        }
#undef G2_LOAD
#undef G2_WRITE
#undef G2_MMA
}

extern "C" void kernel_launch(void* const* d_in, const int* in_sizes, int n_in,
                              void* d_out, int out_size, void* d_ws, size_t ws_size,
                              hipStream_t stream) {
    const float* u          = (const float*)d_in[0];
    const float* log_A_real = (const float*)d_in[1];
    const float* A_imag     = (const float*)d_in[2];
    const float* B_re       = (const float*)d_in[3];
    const float* B_im       = (const float*)d_in[4];
    const float* C_re       = (const float*)d_in[5];
    const float* C_im       = (const float*)d_in[6];
    const float* D          = (const float*)d_in[7];
    const float* log_dt     = (const float*)d_in[8];

    char* wsb = (char*)d_ws;
    float* wsf            = (float*)wsb;
    unsigned short* bw    = (unsigned short*)(wsb + kOffBw);
    unsigned short* cw    = (unsigned short*)(wsb + kOffCw);
    float* finals         = (float*)(wsb + kOffFinals);
    float* carries        = (float*)(wsb + kOffCarries);
    unsigned short* xbf   = (unsigned short*)(wsb + kOffXbf);
    unsigned short* bubf  = (unsigned short*)(wsb + kOffBubf);
    float* y              = (float*)d_out;

    pre1<<<1, 128, 0, stream>>>(log_A_real, A_imag, log_dt, wsf);
    pre2<<<(256 * kF) / 256, 256, 0, stream>>>(B_re, B_im, wsf, bw);
    pre3<<<(kF * 256) / 256, 256, 0, stream>>>(C_re, C_im, cw);

    // Bu(bf16) = u @ Bw^T
    gemm1<<<dim3(2, kM / 128), 256, 0, stream>>>(u, bw, bubf);

    scanA<<<kB * kChunks, 128, 0, stream>>>(bubf, wsf, finals);
    scanB<<<kB, 128, 0, stream>>>(finals, wsf, carries);
    scanC<<<kB * kChunks, 128, 0, stream>>>(bubf, wsf, carries, xbf);

    // y = x @ Cw^T + D*u
    gemm2<<<dim3(kF / 128, kM / 128), 256, 0, stream>>>(xbf, cw, y, D, u);
}

// Round 15
// 95.929 us; speedup vs baseline: 2.2903x; 1.0026x over previous
//
#include <hip/hip_runtime.h>
#include <hip/hip_bf16.h>
#include <math.h>

typedef __attribute__((ext_vector_type(8))) short short8;
typedef __attribute__((ext_vector_type(4))) float f32x4;
typedef __attribute__((ext_vector_type(4))) unsigned int uint4v;

// Problem constants (B=8, S=4096, F=768, N=128)
constexpr int kF = 768;
constexpr int kN = 128;
constexpr int kB = 8;
constexpr int kS = 4096;
constexpr int kM = kB * kS;          // 32768 rows
constexpr int kChunks = 128;         // scan chunks along S (per batch)
constexpr int kClen = 32;

// Workspace layout (BYTE offsets), ~36.5 MB (round 1 used 37.2 MB OK).
// Round 14: Bu is bf16 (16.8 MB) in ws — d_out holds only y.
constexpr size_t kOffBw      = 4096;      // Bw [256][768] bf16
constexpr size_t kOffCw      = 397312;    // Cw [768][256] bf16
constexpr size_t kOffFinals  = 790528;    // finals [1024][256] f32
constexpr size_t kOffCarries = 1839104;   // carries [1024][256] f32
constexpr size_t kOffXbf     = 2887680;   // x_bf16 [32768][256]
constexpr size_t kOffBubf    = 19664896;  // Bu_bf16 [32768][256]

// Software round-to-nearest-even f32->bf16. Round 5 regressed to absmax=0.35
// using __float2bfloat16 (truncation-biased); f2bf is the proven-RNE path.
__device__ __forceinline__ unsigned short f2bf(float f) {
    unsigned int u = __builtin_bit_cast(unsigned int, f);
    u += 0x7fffu + ((u >> 16) & 1u);   // round-to-nearest-even
    return (unsigned short)(u >> 16);
}
__device__ __forceinline__ float bf2f(unsigned short s) {
    unsigned int u = ((unsigned int)s) << 16;
    return __builtin_bit_cast(float, u);
}

__device__ __forceinline__ void gload16(const void* g, void* l) {
    __builtin_amdgcn_global_load_lds(
        (const __attribute__((address_space(1))) void*)g,
        (__attribute__((address_space(3))) void*)l, 16, 0, 0);
}

#define LGKM0_BAR() do { \
    asm volatile("s_waitcnt lgkmcnt(0)" ::: "memory"); \
    __builtin_amdgcn_s_barrier(); \
    __builtin_amdgcn_sched_barrier(0); \
} while (0)

__global__ __launch_bounds__(128)
void pre1(const float* __restrict__ log_A_real, const float* __restrict__ A_imag,
          const float* __restrict__ log_dt, float* __restrict__ ws) {
    int n = threadIdx.x;
    float dt = expf(log_dt[n]);
    float ar = -expf(log_A_real[n]);
    float ai = A_imag[n];
    float er = expf(ar * dt);
    float Ar = er * cosf(ai * dt);
    float Ai = er * sinf(ai * dt);
    float dr = ar + 1e-8f, di = ai;
    float inv = 1.0f / (dr * dr + di * di);
    float nr = Ar - 1.0f, ni = Ai;
    float cr = (nr * dr + ni * di) * inv;
    float ci = (ni * dr - nr * di) * inv;
    float pr = 1.f, pi = 0.f;
    for (int i = 0; i < kClen; ++i) {
        float t = pr * Ar - pi * Ai;
        pi = pr * Ai + pi * Ar;
        pr = t;
    }
    ws[n] = Ar;        ws[128 + n] = Ai;
    ws[256 + n] = pr;  ws[384 + n] = pi;
    ws[512 + n] = cr;  ws[640 + n] = ci;
}

__global__ __launch_bounds__(256)
void pre2(const float* __restrict__ B_re, const float* __restrict__ B_im,
          const float* __restrict__ wsf, unsigned short* __restrict__ bw) {
    int id = blockIdx.x * 256 + threadIdx.x;   // 0 .. 256*768-1
    int c = id / kF;
    int f = id - c * kF;
    int n = c & 127;
    float cr = wsf[512 + n], ci = wsf[640 + n];
    float br = B_re[n * kF + f], bi = B_im[n * kF + f];
    float v = (c < 128) ? (cr * br - ci * bi) : (cr * bi + ci * br);
    bw[id] = f2bf(v);
}

__global__ __launch_bounds__(256)
void pre3(const float* __restrict__ C_re, const float* __restrict__ C_im,
          unsigned short* __restrict__ cw) {
    int id = blockIdx.x * 256 + threadIdx.x;   // 0 .. 768*256-1
    int f = id >> 8;
    int k = id & 255;
    float v = (k < 128) ? C_re[f * kN + k] : -C_im[f * kN + (k - 128)];
    cw[id] = f2bf(v);
}

// GEMM1: Bu_bf16[32768][256] = u[32768][768](f32) @ Bw^T (Bw [256][768] bf16)
// Round-9-exact core (best measured: ~51us): 128x128 tile, BK=32, 24 steps,
// global_load_lds direct staging, 3-slot LDS ring, counted vmcnt(6), m97
// XCD swizzle, XOR-swizzle via pre-swizzled global source. Round-14 change:
// epilogue emits Bu as bf16 RNE (halves write bytes; scan noise analyzed
// safe: linear scan preserves relative error ~2^-9, same order as existing
// x->bf16 rounding).
__global__ __launch_bounds__(256, 2)
void gemm1(const float* __restrict__ A,
           const unsigned short* __restrict__ W,
           unsigned short* __restrict__ Cout) {
    constexpr int K = kF, KT = K / 32;      // 24
    constexpr int SLOT = 24576;             // A 16KB + W 8KB
    __shared__ __align__(16) char smem[3 * SLOT];

    // m97 XCD swizzle (nwg = 512, %8 == 0)
    const int gx = gridDim.x;
    const int nwg = gx * gridDim.y;
    const int orig = blockIdx.y * gx + blockIdx.x;
    const int cpx = nwg >> 3;
    const int sw = (orig & 7) * cpx + (orig >> 3);
    const int m0 = (sw / gx) * 128;
    const int n0 = (sw % gx) * 128;

    const int t = threadIdx.x;
    const int wave = t >> 6, lane = t & 63;
    const int wr = wave >> 1, wc = wave & 1;   // 2x2 waves, each 64x64
    const int lr = lane & 15, lg = lane >> 4;
    const int l3 = lane >> 3, l7 = lane & 7;
    const int uswz = l7 ^ l3;                  // staging source 16B-unit swizzle

    // per-lane global staging bases (instr c adds c*rows*K; tile kt adds kt*32)
    const float* aBase = A + (size_t)(m0 + wave * 32 + l3) * K + uswz * 4;
    const unsigned short* wBase =
        W + (size_t)(n0 + wave * 32 + l3 * 2 + (uswz >> 2)) * K + (uswz & 3) * 8;

    f32x4 acc[4][4] = {};

#define G1_ISSUE(kt_, slotbase_) do { \
    const float* aT_ = aBase + (size_t)(kt_) * 32; \
    const unsigned short* wT_ = wBase + (size_t)(kt_) * 32; \
    char* sA_ = (slotbase_); \
    char* sW_ = (slotbase_) + 16384; \
    _Pragma("unroll") for (int c_ = 0; c_ < 4; ++c_) \
        gload16(aT_ + c_ * 8 * K, sA_ + (wave * 4 + c_) * 1024); \
    _Pragma("unroll") for (int c_ = 0; c_ < 2; ++c_) \
        gload16(wT_ + c_ * 16 * K, sW_ + (wave * 2 + c_) * 1024); \
} while (0)

#define G1_MMA_SLOT(slotbase_) do { \
    const char* sA_ = (slotbase_); \
    const char* sW_ = (slotbase_) + 16384; \
    short8 ah_[4], bh_[4]; \
    _Pragma("unroll") for (int i_ = 0; i_ < 4; ++i_) { \
        const int row_ = wr * 64 + i_ * 16 + lr; \
        const f32x4 fL_ = *(const f32x4*)(sA_ + row_ * 128 + (((lg * 2)     ^ (lr & 7)) * 16)); \
        const f32x4 fH_ = *(const f32x4*)(sA_ + row_ * 128 + (((lg * 2 + 1) ^ (lr & 7)) * 16)); \
        short8 v_; \
        _Pragma("unroll") for (int e_ = 0; e_ < 4; ++e_) { \
            v_[e_]     = (short)f2bf(fL_[e_]); \
            v_[4 + e_] = (short)f2bf(fH_[e_]); \
        } \
        ah_[i_] = v_; \
    } \
    _Pragma("unroll") for (int j_ = 0; j_ < 4; ++j_) { \
        const int row_ = wc * 64 + j_ * 16 + lr; \
        const int d_ = row_ >> 1; \
        const int u_ = (((lr & 1) * 4 + lg) ^ (d_ & 7)) * 16; \
        bh_[j_] = *(const short8*)(sW_ + d_ * 128 + u_); \
    } \
    _Pragma("unroll") for (int i_ = 0; i_ < 4; ++i_) \
    _Pragma("unroll") for (int j_ = 0; j_ < 4; ++j_) \
        acc[i_][j_] = __builtin_amdgcn_mfma_f32_16x16x32_bf16(ah_[i_], bh_[j_], acc[i_][j_], 0, 0, 0); \
} while (0)

    // prologue: tiles 0,1 in flight (6 gll instrs per wave each)
    G1_ISSUE(0, smem);
    G1_ISSUE(1, smem + SLOT);

    int slot = 0;
    for (int kt = 0; kt < KT; ++kt) {
        if (kt < KT - 1) { asm volatile("s_waitcnt vmcnt(6)" ::: "memory"); }
        else             { asm volatile("s_waitcnt vmcnt(0)" ::: "memory"); }
        __builtin_amdgcn_s_barrier();        // all waves' tile-kt staged
        __builtin_amdgcn_sched_barrier(0);
        char* sb = smem + slot * SLOT;
        if (kt + 2 < KT) {
            char* nb = smem + (slot == 0 ? 2 * SLOT : (slot - 1) * SLOT);
            G1_ISSUE(kt + 2, nb);
        }
        G1_MMA_SLOT(sb);
        slot = (slot == 2) ? 0 : slot + 1;
    }

    // epilogue: C/D layout col=lane&15, row=(lane>>4)*4+reg; emit bf16 RNE
#pragma unroll
    for (int i = 0; i < 4; ++i)
#pragma unroll
        for (int j = 0; j < 4; ++j) {
            const int col = n0 + wc * 64 + j * 16 + lr;
#pragma unroll
            for (int q = 0; q < 4; ++q) {
                const int row = m0 + wr * 64 + i * 16 + lg * 4 + q;
                Cout[(size_t)row * 256 + col] = f2bf(acc[i][j][q]);
            }
        }
#undef G1_ISSUE
#undef G1_MMA_SLOT
}

// Phase A: per (b, chunk), local scan (bf16 Bu -> f32 state); save chunk final.
__global__ __launch_bounds__(128)
void scanA(const unsigned short* __restrict__ Bu, const float* __restrict__ wsc,
           float* __restrict__ finals) {
    int n = threadIdx.x;
    int blk = blockIdx.x;            // b*kChunks + c
    int b = blk >> 7, c = blk & 127;
    float Ar = wsc[n], Ai = wsc[128 + n];
    float xr = 0.f, xi = 0.f;
    size_t base = ((size_t)(b * kS + c * kClen)) * 256;
#pragma unroll 8
    for (int s = 0; s < kClen; ++s) {
        float br = bf2f(Bu[base + n]), bi = bf2f(Bu[base + 128 + n]);
        float tr = Ar * xr - Ai * xi + br;
        xi = Ar * xi + Ai * xr + bi;
        xr = tr;
        base += 256;
    }
    finals[(size_t)blk * 256 + n] = xr;
    finals[(size_t)blk * 256 + 128 + n] = xi;
}

// Phase B: serial scan over chunk finals -> exclusive carries.
__global__ __launch_bounds__(128)
void scanB(const float* __restrict__ finals, const float* __restrict__ ws,
           float* __restrict__ carries) {
    int n = threadIdx.x;
    int b = blockIdx.x;
    float Pr = ws[256 + n], Pi = ws[384 + n];
    float xr = 0.f, xi = 0.f;
#pragma unroll 8
    for (int c = 0; c < kChunks; ++c) {
        size_t o = ((size_t)(b * kChunks + c)) * 256;
        carries[o + n] = xr;
        carries[o + 128 + n] = xi;
        float fr = finals[o + n], fi = finals[o + 128 + n];
        float tr = Pr * xr - Pi * xi + fr;
        xi = Pr * xi + Pi * xr + fi;
        xr = tr;
    }
}

// Phase C: seeded local scan (bf16 Bu); emit x as bf16 RNE (GEMM2 input).
__global__ __launch_bounds__(128)
void scanC(const unsigned short* __restrict__ Bu, const float* __restrict__ wsc,
           const float* __restrict__ carries, unsigned short* __restrict__ xbf) {
    int n = threadIdx.x;
    int blk = blockIdx.x;
    int b = blk >> 7, c = blk & 127;
    float Ar = wsc[n], Ai = wsc[128 + n];
    size_t co = (size_t)blk * 256;
    float xr = carries[co + n], xi = carries[co + 128 + n];
    size_t base = ((size_t)(b * kS + c * kClen)) * 256;
#pragma unroll 4
    for (int s = 0; s < kClen; ++s) {
        float br = bf2f(Bu[base + n]), bi = bf2f(Bu[base + 128 + n]);
        float tr = Ar * xr - Ai * xi + br;
        xi = Ar * xi + Ai * xr + bi;
        xr = tr;
        xbf[base + n]       = f2bf(xr);
        xbf[base + 128 + n] = f2bf(xi);
        base += 256;
    }
}

// GEMM2: y[32768][768] = x_bf16[32768][256] @ Cw^T + D*u
// Round-9-exact (proven ~28 us): 128x128 tile, BK=32, 4 waves, lgkm-only
// barriers + 2-deep reg prefetch, m97 chunk XCD swizzle.
__global__ __launch_bounds__(256, 3)
void gemm2(const unsigned short* __restrict__ A,
           const unsigned short* __restrict__ W,
           float* __restrict__ Cout,
           const float* __restrict__ Dp, const float* __restrict__ Up) {
    constexpr int K = 256, KT = 8, Nc = kF;
    __shared__ __align__(16) short As0[128 * 40];
    __shared__ __align__(16) short As1[128 * 40];
    __shared__ __align__(16) short Ws0[128 * 40];
    __shared__ __align__(16) short Ws1[128 * 40];

    const int gx = gridDim.x;
    const int nwg = gx * gridDim.y;
    const int orig = blockIdx.y * gx + blockIdx.x;
    const int cpx = nwg >> 3;
    const int sw = (orig & 7) * cpx + (orig >> 3);
    const int m0 = (sw / gx) * 128;
    const int n0 = (sw % gx) * 128;

    const int t = threadIdx.x;
    const int sr = t >> 1, sh = t & 1;

    const int wave = t >> 6, lane = t & 63;
    const int wr = wave >> 1, wc = wave & 1;
    const int lr = lane & 15, lg = lane >> 4;

    f32x4 acc[4][4] = {};

    uint4v aA0, aA1, aB0, aB1;
    uint4v wA0, wA1, wB0, wB1;
    const unsigned short* aptr = A + (size_t)(m0 + sr) * K + sh * 16;
    const unsigned short* wptr = W + (size_t)(n0 + sr) * K + sh * 16;

#define G2_LOAD(SET, kt) do { \
    const unsigned short* p_ = aptr + (kt) * 32; \
    a##SET##0 = *(const uint4v*)p_; a##SET##1 = *(const uint4v*)(p_ + 8); \
    const unsigned short* q_ = wptr + (kt) * 32; \
    w##SET##0 = *(const uint4v*)q_; w##SET##1 = *(const uint4v*)(q_ + 8); \
} while (0)

#define G2_WRITE(Asb, Wsb, a0, a1, w0, w1) do { \
    const int o_ = sr * 40 + sh * 16; \
    *(short8*)(&Asb[o_])     = *(short8*)&a0; \
    *(short8*)(&Asb[o_ + 8]) = *(short8*)&a1; \
    *(short8*)(&Wsb[o_])     = *(short8*)&w0; \
    *(short8*)(&Wsb[o_ + 8]) = *(short8*)&w1; \
} while (0)

#define G2_MMA(Asb, Wsb) do { \
    short8 ah_[4], bh_[4]; \
    _Pragma("unroll") for (int i_ = 0; i_ < 4; ++i_) { \
        ah_[i_] = *(const short8*)(&Asb[(wr * 64 + i_ * 16 + lr) * 40 + lg * 8]); \
        bh_[i_] = *(const short8*)(&Wsb[(wc * 64 + i_ * 16 + lr) * 40 + lg * 8]); \
    } \
    _Pragma("unroll") for (int i_ = 0; i_ < 4; ++i_) \
    _Pragma("unroll") for (int j_ = 0; j_ < 4; ++j_) \
        acc[i_][j_] = __builtin_amdgcn_mfma_f32_16x16x32_bf16(ah_[i_], bh_[j_], acc[i_][j_], 0, 0, 0); \
} while (0)

    G2_LOAD(A, 0);
    G2_LOAD(B, 1);
    for (int kt = 0; kt < KT; kt += 2) {
        G2_WRITE(As0, Ws0, aA0, aA1, wA0, wA1);
        if (kt + 2 < KT) G2_LOAD(A, kt + 2);
        LGKM0_BAR();
        G2_MMA(As0, Ws0);
        G2_WRITE(As1, Ws1, aB0, aB1, wB0, wB1);
        if (kt + 3 < KT) G2_LOAD(B, kt + 3);
        LGKM0_BAR();
        G2_MMA(As1, Ws1);
    }

#pragma unroll
    for (int i = 0; i < 4; ++i)
#pragma unroll
        for (int j = 0; j < 4; ++j) {
            const int col = n0 + wc * 64 + j * 16 + lr;
#pragma unroll
            for (int q = 0; q < 4; ++q) {
                const int row = m0 + wr * 64 + i * 16 + lg * 4 + q;
                float v = acc[i][j][q];
                v = fmaf(Dp[col], Up[(size_t)row * Nc + col], v);
                Cout[(size_t)row * Nc + col] = v;
            }
        }
#undef G2_LOAD
#undef G2_WRITE
#undef G2_MMA
}

extern "C" void kernel_launch(void* const* d_in, const int* in_sizes, int n_in,
                              void* d_out, int out_size, void* d_ws, size_t ws_size,
                              hipStream_t stream) {
    const float* u          = (const float*)d_in[0];
    const float* log_A_real = (const float*)d_in[1];
    const float* A_imag     = (const float*)d_in[2];
    const float* B_re       = (const float*)d_in[3];
    const float* B_im       = (const float*)d_in[4];
    const float* C_re       = (const float*)d_in[5];
    const float* C_im       = (const float*)d_in[6];
    const float* D          = (const float*)d_in[7];
    const float* log_dt     = (const float*)d_in[8];

    char* wsb = (char*)d_ws;
    float* wsf            = (float*)wsb;
    unsigned short* bw    = (unsigned short*)(wsb + kOffBw);
    unsigned short* cw    = (unsigned short*)(wsb + kOffCw);
    float* finals         = (float*)(wsb + kOffFinals);
    float* carries        = (float*)(wsb + kOffCarries);
    unsigned short* xbf   = (unsigned short*)(wsb + kOffXbf);
    unsigned short* bubf  = (unsigned short*)(wsb + kOffBubf);
    float* y              = (float*)d_out;

    pre1<<<1, 128, 0, stream>>>(log_A_real, A_imag, log_dt, wsf);
    pre2<<<(256 * kF) / 256, 256, 0, stream>>>(B_re, B_im, wsf, bw);
    pre3<<<(kF * 256) / 256, 256, 0, stream>>>(C_re, C_im, cw);

    // Bu(bf16) = u @ Bw^T
    gemm1<<<dim3(2, kM / 128), 256, 0, stream>>>(u, bw, bubf);

    scanA<<<kB * kChunks, 128, 0, stream>>>(bubf, wsf, finals);
    scanB<<<kB, 128, 0, stream>>>(finals, wsf, carries);
    scanC<<<kB * kChunks, 128, 0, stream>>>(bubf, wsf, carries, xbf);

    // y = x @ Cw^T + D*u
    gemm2<<<dim3(kF / 128, kM / 128), 256, 0, stream>>>(xbf, cw, y, D, u);
}